// Round 1
// baseline (142311.377 us; speedup 1.0000x reference)
//
#include <hip/hip_runtime.h>
#include <hip/hip_bf16.h>
#include <hip/hip_cooperative_groups.h>

namespace cg = cooperative_groups;

typedef __hip_bfloat16 bf16;

#define NB   32
#define TE   600
#define TD   600
#define TGT  80
#define PREN 256
#define HID  512
#define ATTD 128
#define LF   32
#define LK   31
#define PH   512

__device__ __forceinline__ float b2f(bf16 x){ return __bfloat162float(x); }

// 8 contiguous bf16 -> fp32 (internal ws tensors only)
__device__ __forceinline__ void ld8bf(const bf16* p, float* o){
  const uint4 u = *(const uint4*)p;
  o[0]=__uint_as_float(u.x<<16); o[1]=__uint_as_float(u.x&0xFFFF0000u);
  o[2]=__uint_as_float(u.y<<16); o[3]=__uint_as_float(u.y&0xFFFF0000u);
  o[4]=__uint_as_float(u.z<<16); o[5]=__uint_as_float(u.z&0xFFFF0000u);
  o[6]=__uint_as_float(u.w<<16); o[7]=__uint_as_float(u.w&0xFFFF0000u);
}

// 8 contiguous fp32
__device__ __forceinline__ void ld8f(const float* p, float* o){
  float4 a=*(const float4*)p, b=*(const float4*)(p+4);
  o[0]=a.x;o[1]=a.y;o[2]=a.z;o[3]=a.w;
  o[4]=b.x;o[5]=b.y;o[6]=b.z;o[7]=b.w;
}

__device__ __forceinline__ float dot8(const float* w, const float* z){
  return w[0]*z[0]+w[1]*z[1]+w[2]*z[2]+w[3]*z[3]
       + w[4]*z[4]+w[5]*z[5]+w[6]*z[6]+w[7]*z[7];
}

__device__ __forceinline__ float sigm(float x){ return 1.f/(1.f+__expf(-x)); }
__device__ __forceinline__ float tanhfast(float x){
  float e = __expf(2.f*x);
  return 1.f - 2.f/(e+1.f);
}

// ---------------- prenet: XS[t][b][256] (bf16) -----------------
__global__ __launch_bounds__(256) void k_prenet(const float* __restrict__ dec,
    const float* __restrict__ w1, const float* __restrict__ b1,
    const float* __restrict__ w2, const float* __restrict__ b2,
    bf16* __restrict__ XS)
{
  int t = blockIdx.x, tid = threadIdx.x;
  __shared__ __align__(16) float fr[NB*TGT];
  __shared__ __align__(16) float h1[NB*PREN];
  for (int i=tid;i<NB*TGT;i+=256){
    int b=i/TGT,c=i%TGT;
    fr[b*TGT+c] = (t==0)?0.f:dec[((size_t)b*TD+(t-1))*TGT+c];
  }
  __syncthreads();
  {
    int oc=tid; float bb=b1[oc];
    const float* wr = w1 + (size_t)oc*TGT;
    for (int b=0;b<NB;b++){
      float acc=bb;
      for (int k=0;k<TGT;k+=8){
        float wv[8]; ld8f(wr+k,wv);
        acc += dot8(wv, fr + b*TGT + k);
      }
      h1[b*PREN+oc]=fmaxf(acc,0.f);
    }
  }
  __syncthreads();
  {
    int oc=tid; float bb=b2[oc];
    const float* wr = w2 + (size_t)oc*PREN;
    for (int b=0;b<NB;b++){
      float acc=bb;
      for (int k=0;k<PREN;k+=8){
        float wv[8]; ld8f(wr+k,wv);
        acc += dot8(wv, h1 + b*PREN + k);
      }
      XS[((size_t)t*NB+b)*PREN+oc]=__float2bfloat16(fmaxf(acc,0.f));
    }
  }
}

// ---------------- proc_mem: PM[b][t][128] (bf16) -----------------
__global__ __launch_bounds__(256) void k_procmem(const float* __restrict__ enc,
    const float* __restrict__ mw, const float* __restrict__ mb, bf16* __restrict__ PM)
{
  int t=blockIdx.x, tid=threadIdx.x;
  __shared__ __align__(16) float xe[16*HID];
  int a = tid & 127, bh = tid >> 7;
  float bb = mb[a];
  const float* wr = mw + (size_t)a*HID;
  for (int half=0; half<2; half++){
    __syncthreads();
    for (int i=tid;i<16*HID;i+=256){
      int bl=i>>9, h=i&511;
      xe[i] = enc[((size_t)(half*16+bl)*TE + t)*HID + h];
    }
    __syncthreads();
    for (int bl=bh*8; bl<bh*8+8; bl++){
      float acc=bb;
      for (int k=0;k<HID;k+=8){
        float wv[8]; ld8f(wr+k,wv);
        acc += dot8(wv, xe + bl*HID + k);
      }
      PM[((size_t)(half*16+bl)*TE + t)*ATTD + a] = __float2bfloat16(acc);
    }
  }
}

// ---------------- persistent scan kernel -----------------
struct ScanP {
  const bf16* XS; const bf16* PM; const float* enc;
  float* MEL;
  float* AH0; float* AH1; float* AC;
  float* DH0; float* DH1; float* DC;
  float* CTX; float* W; float* WC; float* E;
  const float* awih; const float* awhh; const float* abih; const float* abhh;
  const float* dwih; const float* dwhh; const float* dbih; const float* dbhh;
  const float* qw; const float* convw; const float* fcw; const float* vw;
  const float* projw;
};

// attention LSTM, 4 cells per block (blocks 0..127)
__device__ __forceinline__ void lstmA_step(const ScanP& p, int t, int c0, int tid)
{
  int b=tid>>3, j=tid&7;
  const bf16* xs = p.XS + ((size_t)t*NB+b)*PREN;
  const float* cx = p.CTX + b*HID;
  const float* hr = ((t&1)?p.AH1:p.AH0) + b*HID;
  float* hw = (t&1)?p.AH0:p.AH1;
  float acc[16];
  #pragma unroll
  for (int q=0;q<16;q++) acc[q]=0.f;
  for (int i=0;i<20;i++){
    int k8=i*64+j*8;
    float z[8];
    if (k8<256) ld8bf(xs+k8,z);
    else ld8f((k8<768)? cx+(k8-256) : hr+(k8-768), z);
    #pragma unroll
    for (int cc=0;cc<4;cc++){
      #pragma unroll
      for (int g=0;g<4;g++){
        int row = g*HID + c0 + cc;
        const float* wp = (k8<768) ? (p.awih + (size_t)row*768 + k8)
                                   : (p.awhh + (size_t)row*HID + (k8-768));
        float wv[8]; ld8f(wp,wv);
        acc[cc*4+g] += dot8(wv,z);
      }
    }
  }
  #pragma unroll
  for (int q=0;q<16;q++){
    acc[q] += __shfl_xor(acc[q],1);
    acc[q] += __shfl_xor(acc[q],2);
    acc[q] += __shfl_xor(acc[q],4);
  }
  if (j==0){
    #pragma unroll
    for (int cc=0;cc<4;cc++){
      int cell=c0+cc;
      float g0=acc[cc*4+0]+p.abih[0*HID+cell]+p.abhh[0*HID+cell];
      float g1=acc[cc*4+1]+p.abih[1*HID+cell]+p.abhh[1*HID+cell];
      float g2=acc[cc*4+2]+p.abih[2*HID+cell]+p.abhh[2*HID+cell];
      float g3=acc[cc*4+3]+p.abih[3*HID+cell]+p.abhh[3*HID+cell];
      float c2 = sigm(g1)*p.AC[b*HID+cell] + sigm(g0)*tanhfast(g2);
      p.AC[b*HID+cell]=c2;
      hw[b*HID+cell]=sigm(g3)*tanhfast(c2);
    }
  }
}

// decoder LSTM, 4 cells per block (blocks 128..255)
__device__ __forceinline__ void lstmD_step(const ScanP& p, int t, int c0, int tid)
{
  int b=tid>>3, j=tid&7;
  const float* ah  = ((t&1)?p.AH0:p.AH1) + b*HID;   // AH'(t)
  const float* cx  = p.CTX + b*HID;
  const float* dhr = ((t&1)?p.DH1:p.DH0) + b*HID;
  float* dhw = (t&1)?p.DH0:p.DH1;
  float acc[16];
  #pragma unroll
  for (int q=0;q<16;q++) acc[q]=0.f;
  for (int i=0;i<24;i++){
    int k8=i*64+j*8;
    const float* zp = (k8<512)? ah+k8 : (k8<1024)? cx+(k8-512) : dhr+(k8-1024);
    float z[8]; ld8f(zp,z);
    #pragma unroll
    for (int cc=0;cc<4;cc++){
      #pragma unroll
      for (int g=0;g<4;g++){
        int row = g*HID + c0 + cc;
        const float* wp = (k8<1024) ? (p.dwih + (size_t)row*1024 + k8)
                                    : (p.dwhh + (size_t)row*HID + (k8-1024));
        float wv[8]; ld8f(wp,wv);
        acc[cc*4+g] += dot8(wv,z);
      }
    }
  }
  #pragma unroll
  for (int q=0;q<16;q++){
    acc[q] += __shfl_xor(acc[q],1);
    acc[q] += __shfl_xor(acc[q],2);
    acc[q] += __shfl_xor(acc[q],4);
  }
  if (j==0){
    #pragma unroll
    for (int cc=0;cc<4;cc++){
      int cell=c0+cc;
      float g0=acc[cc*4+0]+p.dbih[0*HID+cell]+p.dbhh[0*HID+cell];
      float g1=acc[cc*4+1]+p.dbih[1*HID+cell]+p.dbhh[1*HID+cell];
      float g2=acc[cc*4+2]+p.dbih[2*HID+cell]+p.dbhh[2*HID+cell];
      float g3=acc[cc*4+3]+p.dbih[3*HID+cell]+p.dbhh[3*HID+cell];
      float c2 = sigm(g1)*p.DC[b*HID+cell] + sigm(g0)*tanhfast(g2);
      p.DC[b*HID+cell]=c2;
      dhw[b*HID+cell]=sigm(g3)*tanhfast(c2);
    }
  }
}

// mel for step t-1 (reads DH(t-1), CTX(t-1) which are stable in this phase)
__device__ __forceinline__ void mel_prev(const ScanP& p, int t, int blk, int tid)
{
  if (tid<80){
    int md = blk*10 + (tid>>3);
    int jb = tid&7;
    int o = md%TGT, bb = md/TGT;
    const float* pw = p.projw + (size_t)o*1024;
    const float* dh = ((t&1)?p.DH1:p.DH0) + bb*HID;
    const float* c2 = p.CTX + bb*HID;
    float a=0.f;
    for (int i=0;i<16;i++){
      int k = jb*128 + i*8;
      const float* zp = (k<512)? dh+k : c2+(k-512);
      float z[8]; ld8f(zp,z);
      float wv[8]; ld8f(pw+k,wv);
      a += dot8(wv,z);
    }
    a += __shfl_xor(a,1); a += __shfl_xor(a,2); a += __shfl_xor(a,4);
    if (jb==0) p.MEL[((size_t)bb*TD + (t-1))*TGT + o] = a;
  }
}

__global__ __launch_bounds__(256,1) void k_scan(ScanP p)
{
  cg::grid_group grid = cg::this_grid();
  const int blk = blockIdx.x, tid = threadIdx.x;
  const int b8 = blk>>3;   // batch for B/CD phases
  const int c8 = blk&7;    // chunk (B) / h-quarter (CD)

  // persistent attention weights (loaded once)
  __shared__ float fcs[128*33];
  __shared__ float cw0[32*31], cw1[32*31];
  __shared__ float vv[128];
  // per-step phase B scratch
  __shared__ __align__(16) float wpad[632], wcpad[632];
  __shared__ float qs[128];
  __shared__ float convb[4][32];
  // per-step phase CD scratch
  __shared__ __align__(16) float wl[600];
  __shared__ float part[256];
  __shared__ float red[8];

  for (int i=tid;i<32*31;i+=256){
    int c=i/31, k=i-c*31;
    cw0[i] = p.convw[c*62 + k];
    cw1[i] = p.convw[c*62 + 31 + k];
  }
  for (int i=tid;i<128*33;i+=256){
    int a=i/33, c=i-a*33;
    fcs[i] = (c<32)? p.fcw[a*32+c] : 0.f;
  }
  if (tid<128) vv[tid]=p.vw[tid];
  __syncthreads();

  // prologue: lstmA(0)
  if (blk<128) lstmA_step(p, 0, blk*4, tid);
  grid.sync();

  for (int t=0;t<TD;t++){
    const float* AHn = (t&1)?p.AH0:p.AH1;   // AH'(t)

    // ---------- phase B: energies + mel(t-1) ----------
    {
      int b=b8, chunk=c8;
      for (int i=tid;i<630;i+=256){
        wpad[i]  = (i>=15 && i<615) ? p.W [(size_t)b*TE + i-15] : 0.f;
        wcpad[i] = (i>=15 && i<615) ? p.WC[(size_t)b*TE + i-15] : 0.f;
      }
      if (tid<128){
        const float* qr = p.qw + (size_t)tid*HID;
        const float* ah = AHn + b*HID;
        float acc=0.f;
        for (int k=0;k<HID;k+=8){
          float wv[8]; ld8f(qr+k,wv);
          acc += dot8(wv, ah+k);
        }
        qs[tid]=acc;
      }
      if (t>0) mel_prev(p, t, blk, tid);
      __syncthreads();
      int wid=tid>>6, lane=tid&63;
      int tbase=chunk*75;
      for (int it=0; it<19; it++){
        int tt = tbase + it*4 + wid;
        bool act = (tt < tbase+75);
        if (act && lane<32){
          int c=lane; float s=0.f;
          for (int k=0;k<LK;k++)
            s += cw0[c*31+k]*wpad[tt+k] + cw1[c*31+k]*wcpad[tt+k];
          convb[wid][c]=s;
        }
        __syncthreads();
        if (act){
          float partl=0.f;
          #pragma unroll
          for (int half=0;half<2;half++){
            int a=lane+half*64;
            float loc=0.f;
            #pragma unroll
            for (int c=0;c<32;c++) loc += fcs[a*33+c]*convb[wid][c];
            float x = qs[a] + b2f(p.PM[((size_t)b*TE+tt)*ATTD + a]) + loc;
            partl += vv[a]*tanhfast(x);
          }
          for (int off=1; off<64; off<<=1) partl += __shfl_xor(partl, off);
          if (lane==0) p.E[(size_t)b*TE + tt] = partl;
        }
        __syncthreads();
      }
    }
    grid.sync();

    // ---------- phase CD: softmax (redundant per block) + ctx quarter ----------
    {
      int b=b8, q4=c8;
      float e0[3]; float mx=-1e30f;
      #pragma unroll
      for (int r=0;r<3;r++){
        int i=tid+r*256;
        float v=(i<TE)? p.E[(size_t)b*TE+i] : -1e30f;
        e0[r]=v; mx=fmaxf(mx,v);
      }
      for (int off=1;off<64;off<<=1) mx=fmaxf(mx,__shfl_xor(mx,off));
      if ((tid&63)==0) red[tid>>6]=mx;
      __syncthreads();
      float m=fmaxf(fmaxf(red[0],red[1]),fmaxf(red[2],red[3]));
      float ex[3]; float s=0.f;
      #pragma unroll
      for (int r=0;r<3;r++){
        int i=tid+r*256;
        ex[r]=(i<TE)? __expf(e0[r]-m) : 0.f;
        s+=ex[r];
      }
      for (int off=1;off<64;off<<=1) s+=__shfl_xor(s,off);
      __syncthreads();
      if ((tid&63)==0) red[tid>>6]=s;
      __syncthreads();
      float inv=1.f/(red[0]+red[1]+red[2]+red[3]);
      #pragma unroll
      for (int r=0;r<3;r++){
        int i=tid+r*256;
        if (i<TE){
          float w2=ex[r]*inv;
          wl[i]=w2;
          if (q4==0){
            p.W[(size_t)b*TE+i]=w2;
            p.WC[(size_t)b*TE+i]+=w2;
          }
        }
      }
      __syncthreads();
      {
        int hl=tid&63, tj=tid>>6;
        int h=q4*64+hl;
        const float* ep = p.enc + ((size_t)b*TE)*HID + h;
        float a0=0.f, a1=0.f;
        int tb_=tj*150;
        #pragma unroll 5
        for (int tt=tb_; tt<tb_+150; tt+=2){
          a0 += wl[tt]  *ep[(size_t)(tt  )*HID];
          a1 += wl[tt+1]*ep[(size_t)(tt+1)*HID];
        }
        part[tj*64+hl]=a0+a1;
      }
      __syncthreads();
      if (tid<64){
        float v=part[tid]+part[64+tid]+part[128+tid]+part[192+tid];
        p.CTX[b*HID + q4*64 + tid]=v;
      }
    }
    grid.sync();

    // ---------- phase EA: lstmD(t) || lstmA(t+1) ----------
    if (blk<128){
      if (t+1<TD) lstmA_step(p, t+1, blk*4, tid);
    } else {
      lstmD_step(p, t, (blk-128)*4, tid);
    }
    grid.sync();
  }

  // final mel (step 599): DH(599) is in parity slot of t=600, CTX holds CTX(599)
  mel_prev(p, TD, blk, tid);
}

// ---------------- postnet conv (generic, bf16 internal activations) --------
__global__ __launch_bounds__(256) void k_conv(
    const void* __restrict__ inv_, bf16* __restrict__ out,
    const float* __restrict__ w, const float* __restrict__ bias,
    int IC, int OC, int mel_in, int do_tanh, int b0)
{
  __shared__ __align__(16) float xs[256*36];
  int bl=blockIdx.x, bg=b0+bl, oct=blockIdx.y, t0=blockIdx.z*32, tid=threadIdx.x;
  int oc = oct*256 + tid;
  float acc[32];
  #pragma unroll
  for (int q=0;q<32;q++) acc[q]=0.f;
  int nch=(IC+255)/256;
  const float* inf_ = (const float*)inv_;
  const bf16*  inb_ = (const bf16*)inv_;
  for (int ch=0;ch<nch;ch++){
    int icb=ch*256, icn=min(256,IC-icb);
    __syncthreads();
    for (int i=tid;i<icn*36;i+=256){
      int icl=i/36, tt=i-icl*36;
      int tg=t0+tt-2;
      float v=0.f;
      if (tg>=0 && tg<TD){
        int ic=icb+icl;
        v = mel_in ? inf_[((size_t)bg*TD+tg)*TGT+ic]
                   : b2f(inb_[((size_t)bl*IC+ic)*TD+tg]);
      }
      xs[i]=v;
    }
    __syncthreads();
    if (oc<OC){
      const float* wp = w + ((size_t)oc*IC+icb)*5;
      for (int ic=0;ic<icn;ic++){
        float xw[36];
        #pragma unroll
        for (int q=0;q<9;q++) ((float4*)xw)[q]=((const float4*)(xs+ic*36))[q];
        float wk0=wp[ic*5  ],wk1=wp[ic*5+1],wk2=wp[ic*5+2],
              wk3=wp[ic*5+3],wk4=wp[ic*5+4];
        #pragma unroll
        for (int tt=0;tt<32;tt++)
          acc[tt] += wk0*xw[tt]+wk1*xw[tt+1]+wk2*xw[tt+2]+wk3*xw[tt+3]+wk4*xw[tt+4];
      }
    }
  }
  if (oc<OC){
    float bv=bias[oc];
    for (int tt=0;tt<32;tt++){
      int tg=t0+tt;
      if (tg<TD){
        float v=acc[tt]+bv;
        if (do_tanh) v=tanhfast(v);
        out[((size_t)bl*OC+oc)*TD+tg]=__float2bfloat16(v);
      }
    }
  }
}

// ---------------- postnet last layer + in-place residual on d_out ----------
__global__ __launch_bounds__(256) void k_conv_last(
    const bf16* __restrict__ in, const float* __restrict__ w,
    const float* __restrict__ bias, float* __restrict__ outp, int b0)
{
  __shared__ __align__(16) float xs[256*36];
  int bl=blockIdx.x, bg=b0+bl, t0=blockIdx.z*32, tid=threadIdx.x;
  int oc = tid;
  float acc[32];
  #pragma unroll
  for (int q=0;q<32;q++) acc[q]=0.f;
  for (int ch=0;ch<2;ch++){
    int icb=ch*256;
    __syncthreads();
    for (int i=tid;i<256*36;i+=256){
      int icl=i/36, tt=i-icl*36;
      int tg=t0+tt-2;
      float v=0.f;
      if (tg>=0 && tg<TD){
        int ic=icb+icl;
        v = b2f(in[((size_t)bl*PH+ic)*TD+tg]);
      }
      xs[i]=v;
    }
    __syncthreads();
    if (oc<TGT){
      const float* wp = w + ((size_t)oc*PH+icb)*5;
      for (int ic=0;ic<256;ic++){
        float xw[36];
        #pragma unroll
        for (int q=0;q<9;q++) ((float4*)xw)[q]=((const float4*)(xs+ic*36))[q];
        float wk0=wp[ic*5  ],wk1=wp[ic*5+1],wk2=wp[ic*5+2],
              wk3=wp[ic*5+3],wk4=wp[ic*5+4];
        #pragma unroll
        for (int tt=0;tt<32;tt++)
          acc[tt] += wk0*xw[tt]+wk1*xw[tt+1]+wk2*xw[tt+2]+wk3*xw[tt+3]+wk4*xw[tt+4];
      }
    }
  }
  if (oc<TGT){
    float bv=bias[oc];
    for (int tt=0;tt<32;tt++){
      int tg=t0+tt;
      if (tg<TD){
        size_t idx=((size_t)bg*TD+tg)*TGT+oc;
        outp[idx]=acc[tt]+bv+outp[idx];
      }
    }
  }
}

extern "C" void kernel_launch(void* const* d_in, const int* in_sizes, int n_in,
                              void* d_out, int out_size, void* d_ws, size_t ws_size,
                              hipStream_t stream)
{
  const float* enc =(const float*)d_in[0];
  const float* dec =(const float*)d_in[1];
  const float* pw1 =(const float*)d_in[2];  const float* pb1=(const float*)d_in[3];
  const float* pw2 =(const float*)d_in[4];  const float* pb2=(const float*)d_in[5];
  const float* awih=(const float*)d_in[6];  const float* awhh=(const float*)d_in[7];
  const float* abih=(const float*)d_in[8];  const float* abhh=(const float*)d_in[9];
  const float* dwih=(const float*)d_in[10]; const float* dwhh=(const float*)d_in[11];
  const float* dbih=(const float*)d_in[12]; const float* dbhh=(const float*)d_in[13];
  const float* memw=(const float*)d_in[14]; const float* memb=(const float*)d_in[15];
  const float* qw  =(const float*)d_in[16];
  const float* lcw =(const float*)d_in[17];
  const float* lfw =(const float*)d_in[18];
  const float* vw  =(const float*)d_in[19];
  const float* pjw =(const float*)d_in[20];
  const float* cwt0=(const float*)d_in[21]; const float* cbt0=(const float*)d_in[22];
  const float* cwt1=(const float*)d_in[23]; const float* cbt1=(const float*)d_in[24];
  const float* cwt2=(const float*)d_in[25]; const float* cbt2=(const float*)d_in[26];
  const float* cwt3=(const float*)d_in[27]; const float* cbt3=(const float*)d_in[28];
  const float* cwt4=(const float*)d_in[29]; const float* cbt4=(const float*)d_in[30];
  float* MEL = (float*)d_out;
  (void)in_sizes; (void)n_in; (void)out_size; (void)ws_size;

  // ---- workspace layout (same as previous version): ----
  char* base=(char*)d_ws;
  const size_t XS_B = (size_t)TD*NB*PREN*2;   //  9,830,400 B
  const size_t PM_B = (size_t)NB*TE*ATTD*2;   //  4,915,200 B
  const size_t HB   = (size_t)NB*HID*4;       //     65,536 B
  const size_t WB   = (size_t)NB*TE*4;        //     76,800 B
  bf16* XSb = (bf16*)base;
  bf16* PMb = (bf16*)(base + XS_B);
  char* sbase = base + XS_B + PM_B;
  float* AH0=(float*)(sbase+0*HB);
  float* AH1=(float*)(sbase+1*HB);
  float* ACb=(float*)(sbase+2*HB);
  float* DH0=(float*)(sbase+3*HB);
  float* DH1=(float*)(sbase+4*HB);
  float* DCb=(float*)(sbase+5*HB);
  float* CTX=(float*)(sbase+6*HB);
  float* Wb =(float*)(sbase+7*HB);
  float* WC =(float*)(sbase+7*HB+WB);
  float* Eb =(float*)(sbase+7*HB+2*WB);
  const int G = 8;
  const size_t PBc_B = (size_t)G*PH*TD*2;
  bf16* PB0 = (bf16*)base;
  bf16* PB1 = (bf16*)(base + PBc_B);

  hipMemsetAsync(sbase, 0, 7*HB+3*WB, stream);

  k_prenet<<<TD,256,0,stream>>>(dec,pw1,pb1,pw2,pb2,XSb);
  k_procmem<<<TE,256,0,stream>>>(enc,memw,memb,PMb);

  ScanP sp;
  sp.XS=XSb; sp.PM=PMb; sp.enc=enc; sp.MEL=MEL;
  sp.AH0=AH0; sp.AH1=AH1; sp.AC=ACb;
  sp.DH0=DH0; sp.DH1=DH1; sp.DC=DCb;
  sp.CTX=CTX; sp.W=Wb; sp.WC=WC; sp.E=Eb;
  sp.awih=awih; sp.awhh=awhh; sp.abih=abih; sp.abhh=abhh;
  sp.dwih=dwih; sp.dwhh=dwhh; sp.dbih=dbih; sp.dbhh=dbhh;
  sp.qw=qw; sp.convw=lcw; sp.fcw=lfw; sp.vw=vw; sp.projw=pjw;
  void* kargs[] = { (void*)&sp };
  hipLaunchCooperativeKernel((const void*)k_scan, dim3(256), dim3(256),
                             kargs, 0, stream);

  // postnet in 4 batch-chunks of G=8 (buffers fit the dead XS region)
  for (int c=0;c<NB/G;c++){
    int b0=c*G;
    k_conv<<<dim3(G,2,19),256,0,stream>>>(MEL,PB0,cwt0,cbt0,TGT,PH,1,1,b0);
    k_conv<<<dim3(G,2,19),256,0,stream>>>(PB0,PB1,cwt1,cbt1,PH,PH,0,1,b0);
    k_conv<<<dim3(G,2,19),256,0,stream>>>(PB1,PB0,cwt2,cbt2,PH,PH,0,1,b0);
    k_conv<<<dim3(G,2,19),256,0,stream>>>(PB0,PB1,cwt3,cbt3,PH,PH,0,1,b0);
    k_conv_last<<<dim3(G,1,19),256,0,stream>>>(PB1,cwt4,cbt4,MEL,b0);
  }
}

// Round 2
// 88788.788 us; speedup vs baseline: 1.6028x; 1.6028x over previous
//
#include <hip/hip_runtime.h>
#include <hip/hip_bf16.h>

typedef __hip_bfloat16 bf16;

#define NB   32
#define TE   600
#define TD   600
#define TGT  80
#define PREN 256
#define HID  512
#define ATTD 128
#define LF   32
#define LK   31
#define PH   512

__device__ __forceinline__ float b2f(bf16 x){ return __bfloat162float(x); }

// 8 contiguous bf16 -> fp32 (internal ws tensors only)
__device__ __forceinline__ void ld8bf(const bf16* p, float* o){
  const uint4 u = *(const uint4*)p;
  o[0]=__uint_as_float(u.x<<16); o[1]=__uint_as_float(u.x&0xFFFF0000u);
  o[2]=__uint_as_float(u.y<<16); o[3]=__uint_as_float(u.y&0xFFFF0000u);
  o[4]=__uint_as_float(u.z<<16); o[5]=__uint_as_float(u.z&0xFFFF0000u);
  o[6]=__uint_as_float(u.w<<16); o[7]=__uint_as_float(u.w&0xFFFF0000u);
}

// 8 contiguous fp32
__device__ __forceinline__ void ld8f(const float* p, float* o){
  float4 a=*(const float4*)p, b=*(const float4*)(p+4);
  o[0]=a.x;o[1]=a.y;o[2]=a.z;o[3]=a.w;
  o[4]=b.x;o[5]=b.y;o[6]=b.z;o[7]=b.w;
}

__device__ __forceinline__ float dot8(const float* w, const float* z){
  return w[0]*z[0]+w[1]*z[1]+w[2]*z[2]+w[3]*z[3]
       + w[4]*z[4]+w[5]*z[5]+w[6]*z[6]+w[7]*z[7];
}

__device__ __forceinline__ float sigm(float x){ return 1.f/(1.f+__expf(-x)); }
__device__ __forceinline__ float tanhfast(float x){
  float e = __expf(2.f*x);
  return 1.f - 2.f/(e+1.f);
}

// ---------------- prenet: XS[t][b][256] (bf16) -----------------
__global__ __launch_bounds__(256) void k_prenet(const float* __restrict__ dec,
    const float* __restrict__ w1, const float* __restrict__ b1,
    const float* __restrict__ w2, const float* __restrict__ b2,
    bf16* __restrict__ XS)
{
  int t = blockIdx.x, tid = threadIdx.x;
  __shared__ __align__(16) float fr[NB*TGT];
  __shared__ __align__(16) float h1[NB*PREN];
  for (int i=tid;i<NB*TGT;i+=256){
    int b=i/TGT,c=i%TGT;
    fr[b*TGT+c] = (t==0)?0.f:dec[((size_t)b*TD+(t-1))*TGT+c];
  }
  __syncthreads();
  {
    int oc=tid; float bb=b1[oc];
    const float* wr = w1 + (size_t)oc*TGT;
    for (int b=0;b<NB;b++){
      float acc=bb;
      for (int k=0;k<TGT;k+=8){
        float wv[8]; ld8f(wr+k,wv);
        acc += dot8(wv, fr + b*TGT + k);
      }
      h1[b*PREN+oc]=fmaxf(acc,0.f);
    }
  }
  __syncthreads();
  {
    int oc=tid; float bb=b2[oc];
    const float* wr = w2 + (size_t)oc*PREN;
    for (int b=0;b<NB;b++){
      float acc=bb;
      for (int k=0;k<PREN;k+=8){
        float wv[8]; ld8f(wr+k,wv);
        acc += dot8(wv, h1 + b*PREN + k);
      }
      XS[((size_t)t*NB+b)*PREN+oc]=__float2bfloat16(fmaxf(acc,0.f));
    }
  }
}

// ---------------- proc_mem: PM[b][t][128] (bf16) -----------------
__global__ __launch_bounds__(256) void k_procmem(const float* __restrict__ enc,
    const float* __restrict__ mw, const float* __restrict__ mb, bf16* __restrict__ PM)
{
  int t=blockIdx.x, tid=threadIdx.x;
  __shared__ __align__(16) float xe[16*HID];
  int a = tid & 127, bh = tid >> 7;
  float bb = mb[a];
  const float* wr = mw + (size_t)a*HID;
  for (int half=0; half<2; half++){
    __syncthreads();
    for (int i=tid;i<16*HID;i+=256){
      int bl=i>>9, h=i&511;
      xe[i] = enc[((size_t)(half*16+bl)*TE + t)*HID + h];
    }
    __syncthreads();
    for (int bl=bh*8; bl<bh*8+8; bl++){
      float acc=bb;
      for (int k=0;k<HID;k+=8){
        float wv[8]; ld8f(wr+k,wv);
        acc += dot8(wv, xe + bl*HID + k);
      }
      PM[((size_t)(half*16+bl)*TE + t)*ATTD + a] = __float2bfloat16(acc);
    }
  }
}

// ---------------- phase 1: energies + q-proj + mel(t-1) -----------------
// grid 256 (b = blk&31, chunk = blk>>5), block 256
__global__ __launch_bounds__(256) void k_att1m(
    const float* __restrict__ AHn, const float* __restrict__ W,
    const float* __restrict__ WCUM, const bf16* __restrict__ PM,
    float* __restrict__ E,
    const float* __restrict__ qw, const float* __restrict__ convw,
    const float* __restrict__ fcw, const float* __restrict__ vw,
    const float* __restrict__ DHp, const float* __restrict__ CTX,
    const float* __restrict__ projw, float* __restrict__ MEL, int t)
{
  int blk = blockIdx.x, tid = threadIdx.x;
  int b = blk & 31, chunk = blk >> 5;
  __shared__ __align__(16) float wpad[632], wcpad[632], qs[128], vv[128];
  __shared__ __align__(16) float fcs[128*33];
  __shared__ __align__(16) float cw0[32*31], cw1[32*31];
  __shared__ __align__(16) float convb[4][32];
  for (int i=tid;i<630;i+=256){
    wpad[i]  = (i>=15 && i<615) ? W[(size_t)b*TE + i-15] : 0.f;
    wcpad[i] = (i>=15 && i<615) ? WCUM[(size_t)b*TE + i-15] : 0.f;
  }
  for (int i=tid;i<32*31;i+=256){
    int c=i/31, k=i-c*31;
    cw0[i] = convw[c*62 + k];
    cw1[i] = convw[c*62 + 31 + k];
  }
  for (int i=tid;i<128*33;i+=256){
    int a=i/33, c=i-a*33;
    fcs[i] = (c<32)? fcw[a*32+c] : 0.f;
  }
  if (tid < 128){
    vv[tid] = vw[tid];
    const float* qr = qw + (size_t)tid*HID;
    const float* ah = AHn + b*HID;
    float acc = 0.f;
    for (int k=0;k<HID;k+=8){
      float wv[8]; ld8f(qr+k,wv);
      acc += dot8(wv, ah+k);
    }
    qs[tid] = acc;
  }
  // mel for step t-1: reads DH(t-1), CTX(t-1) -- both stable this phase
  if (t>0 && tid<80){
    int md = blk*10 + (tid>>3);
    int jb = tid&7;
    int o = md%TGT, bb = md/TGT;
    const float* pw = projw + (size_t)o*1024;
    const float* dh = DHp + bb*HID;
    const float* c2 = CTX + bb*HID;
    float a=0.f;
    for (int i=0;i<16;i++){
      int k = jb*128 + i*8;
      const float* zp = (k<512)? dh+k : c2+(k-512);
      float z[8]; ld8f(zp,z);
      float wv[8]; ld8f(pw+k,wv);
      a += dot8(wv,z);
    }
    a += __shfl_xor(a,1); a += __shfl_xor(a,2); a += __shfl_xor(a,4);
    if (jb==0) MEL[((size_t)bb*TD + (t-1))*TGT + o] = a;
  }
  __syncthreads();
  int wid = tid>>6, lane = tid&63;
  int tbase = chunk*75;
  for (int it=0; it<19; it++){
    int tt = tbase + it*4 + wid;
    bool act = (tt < tbase+75);
    if (act && lane < 32){
      int c = lane; float s = 0.f;
      for (int k=0;k<LK;k++)
        s += cw0[c*31+k]*wpad[tt+k] + cw1[c*31+k]*wcpad[tt+k];
      convb[wid][c] = s;
    }
    __syncthreads();
    if (act){
      float part = 0.f;
      #pragma unroll
      for (int half=0; half<2; half++){
        int a = lane + half*64;
        float loc = 0.f;
        #pragma unroll
        for (int c=0;c<32;c++) loc += fcs[a*33+c]*convb[wid][c];
        float x = qs[a] + b2f(PM[((size_t)b*TE + tt)*ATTD + a]) + loc;
        part += vv[a]*tanhfast(x);
      }
      for (int off=1; off<64; off<<=1) part += __shfl_xor(part, off);
      if (lane==0) E[(size_t)b*TE + tt] = part;
    }
    __syncthreads();
  }
}

// ---------------- phase 2: softmax (redundant per block) + ctx quarter ----
// grid 256 (b = blk>>3, q4 = blk&7), block 256
__global__ __launch_bounds__(256) void k_att23(const float* __restrict__ E,
    float* __restrict__ W, float* __restrict__ WCUM,
    const float* __restrict__ enc, float* __restrict__ CTX)
{
  int blk=blockIdx.x, tid=threadIdx.x;
  int b = blk>>3, q4 = blk&7;
  __shared__ __align__(16) float wl[600];
  __shared__ float part[256];
  __shared__ float red[4];
  float e0[3]; float mx=-1e30f;
  #pragma unroll
  for (int r=0;r<3;r++){
    int i=tid+r*256;
    float v=(i<TE)? E[(size_t)b*TE+i] : -1e30f;
    e0[r]=v; mx=fmaxf(mx,v);
  }
  for (int off=1;off<64;off<<=1) mx=fmaxf(mx,__shfl_xor(mx,off));
  if ((tid&63)==0) red[tid>>6]=mx;
  __syncthreads();
  float m=fmaxf(fmaxf(red[0],red[1]),fmaxf(red[2],red[3]));
  float ex[3]; float s=0.f;
  #pragma unroll
  for (int r=0;r<3;r++){
    int i=tid+r*256;
    ex[r]=(i<TE)? __expf(e0[r]-m) : 0.f;
    s+=ex[r];
  }
  for (int off=1;off<64;off<<=1) s+=__shfl_xor(s,off);
  __syncthreads();
  if ((tid&63)==0) red[tid>>6]=s;
  __syncthreads();
  float inv=1.f/(red[0]+red[1]+red[2]+red[3]);
  #pragma unroll
  for (int r=0;r<3;r++){
    int i=tid+r*256;
    if (i<TE){
      float w2=ex[r]*inv;
      wl[i]=w2;
      if (q4==0){
        W[(size_t)b*TE+i]=w2;
        WCUM[(size_t)b*TE+i]+=w2;
      }
    }
  }
  __syncthreads();
  {
    int hl=tid&63, tj=tid>>6;
    int h=q4*64+hl;
    const float* ep = enc + ((size_t)b*TE)*HID + h;
    float a0=0.f, a1=0.f;
    int tb_=tj*150;
    #pragma unroll 5
    for (int tt=tb_; tt<tb_+150; tt+=2){
      a0 += wl[tt]  *ep[(size_t)(tt  )*HID];
      a1 += wl[tt+1]*ep[(size_t)(tt+1)*HID];
    }
    part[tj*64+hl]=a0+a1;
  }
  __syncthreads();
  if (tid<64){
    float v=part[tid]+part[64+tid]+part[128+tid]+part[192+tid];
    CTX[b*HID + q4*64 + tid]=v;
  }
}

// ---------------- phase 3: lstmD(t) || lstmA(t+1) -----------------
// blocks 0..127: lstmA step t+1 (4 cells); blocks 128..255: lstmD step t (4 cells)
__global__ __launch_bounds__(256) void k_lstmAD(
    const bf16* __restrict__ XS, const float* __restrict__ CTX,
    float* __restrict__ AH0, float* __restrict__ AH1, float* __restrict__ AC,
    float* __restrict__ DH0, float* __restrict__ DH1, float* __restrict__ DC,
    const float* __restrict__ awih, const float* __restrict__ awhh,
    const float* __restrict__ abih, const float* __restrict__ abhh,
    const float* __restrict__ dwih, const float* __restrict__ dwhh,
    const float* __restrict__ dbih, const float* __restrict__ dbhh,
    int t)
{
  int blk=blockIdx.x, tid=threadIdx.x;
  int b=tid>>3, j=tid&7;
  if (blk<128){
    int s = t+1;                       // attention-LSTM step
    if (s>=TD) return;
    int c0 = blk*4;
    const bf16* xs = XS + ((size_t)s*NB+b)*PREN;
    const float* cx = CTX + b*HID;
    const float* hr = ((s&1)?AH1:AH0) + b*HID;
    float* hw = (s&1)?AH0:AH1;
    float acc[16];
    #pragma unroll
    for (int q=0;q<16;q++) acc[q]=0.f;
    for (int i=0;i<20;i++){
      int k8=i*64+j*8;
      float z[8];
      if (k8<256) ld8bf(xs+k8,z);
      else ld8f((k8<768)? cx+(k8-256) : hr+(k8-768), z);
      #pragma unroll
      for (int cc=0;cc<4;cc++){
        #pragma unroll
        for (int g=0;g<4;g++){
          int row = g*HID + c0 + cc;
          const float* wp = (k8<768) ? (awih + (size_t)row*768 + k8)
                                     : (awhh + (size_t)row*HID + (k8-768));
          float wv[8]; ld8f(wp,wv);
          acc[cc*4+g] += dot8(wv,z);
        }
      }
    }
    #pragma unroll
    for (int q=0;q<16;q++){
      acc[q] += __shfl_xor(acc[q],1);
      acc[q] += __shfl_xor(acc[q],2);
      acc[q] += __shfl_xor(acc[q],4);
    }
    if (j==0){
      #pragma unroll
      for (int cc=0;cc<4;cc++){
        int cell=c0+cc;
        float g0=acc[cc*4+0]+abih[0*HID+cell]+abhh[0*HID+cell];
        float g1=acc[cc*4+1]+abih[1*HID+cell]+abhh[1*HID+cell];
        float g2=acc[cc*4+2]+abih[2*HID+cell]+abhh[2*HID+cell];
        float g3=acc[cc*4+3]+abih[3*HID+cell]+abhh[3*HID+cell];
        float c2 = sigm(g1)*AC[b*HID+cell] + sigm(g0)*tanhfast(g2);
        AC[b*HID+cell]=c2;
        hw[b*HID+cell]=sigm(g3)*tanhfast(c2);
      }
    }
  } else {
    if (t<0) return;
    int c0 = (blk-128)*4;
    const float* ah  = ((t&1)?AH0:AH1) + b*HID;   // AH'(t)
    const float* cx  = CTX + b*HID;
    const float* dhr = ((t&1)?DH1:DH0) + b*HID;
    float* dhw = (t&1)?DH0:DH1;
    float acc[16];
    #pragma unroll
    for (int q=0;q<16;q++) acc[q]=0.f;
    for (int i=0;i<24;i++){
      int k8=i*64+j*8;
      const float* zp = (k8<512)? ah+k8 : (k8<1024)? cx+(k8-512) : dhr+(k8-1024);
      float z[8]; ld8f(zp,z);
      #pragma unroll
      for (int cc=0;cc<4;cc++){
        #pragma unroll
        for (int g=0;g<4;g++){
          int row = g*HID + c0 + cc;
          const float* wp = (k8<1024) ? (dwih + (size_t)row*1024 + k8)
                                      : (dwhh + (size_t)row*HID + (k8-1024));
          float wv[8]; ld8f(wp,wv);
          acc[cc*4+g] += dot8(wv,z);
        }
      }
    }
    #pragma unroll
    for (int q=0;q<16;q++){
      acc[q] += __shfl_xor(acc[q],1);
      acc[q] += __shfl_xor(acc[q],2);
      acc[q] += __shfl_xor(acc[q],4);
    }
    if (j==0){
      #pragma unroll
      for (int cc=0;cc<4;cc++){
        int cell=c0+cc;
        float g0=acc[cc*4+0]+dbih[0*HID+cell]+dbhh[0*HID+cell];
        float g1=acc[cc*4+1]+dbih[1*HID+cell]+dbhh[1*HID+cell];
        float g2=acc[cc*4+2]+dbih[2*HID+cell]+dbhh[2*HID+cell];
        float g3=acc[cc*4+3]+dbih[3*HID+cell]+dbhh[3*HID+cell];
        float c2 = sigm(g1)*DC[b*HID+cell] + sigm(g0)*tanhfast(g2);
        DC[b*HID+cell]=c2;
        dhw[b*HID+cell]=sigm(g3)*tanhfast(c2);
      }
    }
  }
}

// ---------------- final-step mel -----------------
__global__ __launch_bounds__(256) void k_melfinal(const float* __restrict__ DH,
    const float* __restrict__ CTX, const float* __restrict__ projw, float* __restrict__ MEL)
{
  int gid=blockIdx.x*256+threadIdx.x;
  if (gid>=NB*TGT) return;
  int o=gid%TGT, b=gid/TGT;
  const float* pw=projw+(size_t)o*1024;
  float a=0.f;
  for (int k=0;k<HID;k+=8){
    float wv[8]; ld8f(pw+k,wv);
    a += dot8(wv, DH + b*HID + k);
  }
  for (int k=0;k<HID;k+=8){
    float wv[8]; ld8f(pw+512+k,wv);
    a += dot8(wv, CTX + b*HID + k);
  }
  MEL[((size_t)b*TD+599)*TGT+o]=a;
}

// ---------------- postnet conv (generic, bf16 internal activations) --------
__global__ __launch_bounds__(256) void k_conv(
    const void* __restrict__ inv_, bf16* __restrict__ out,
    const float* __restrict__ w, const float* __restrict__ bias,
    int IC, int OC, int mel_in, int do_tanh, int b0)
{
  __shared__ __align__(16) float xs[256*36];
  int bl=blockIdx.x, bg=b0+bl, oct=blockIdx.y, t0=blockIdx.z*32, tid=threadIdx.x;
  int oc = oct*256 + tid;
  float acc[32];
  #pragma unroll
  for (int q=0;q<32;q++) acc[q]=0.f;
  int nch=(IC+255)/256;
  const float* inf_ = (const float*)inv_;
  const bf16*  inb_ = (const bf16*)inv_;
  for (int ch=0;ch<nch;ch++){
    int icb=ch*256, icn=min(256,IC-icb);
    __syncthreads();
    for (int i=tid;i<icn*36;i+=256){
      int icl=i/36, tt=i-icl*36;
      int tg=t0+tt-2;
      float v=0.f;
      if (tg>=0 && tg<TD){
        int ic=icb+icl;
        v = mel_in ? inf_[((size_t)bg*TD+tg)*TGT+ic]
                   : b2f(inb_[((size_t)bl*IC+ic)*TD+tg]);
      }
      xs[i]=v;
    }
    __syncthreads();
    if (oc<OC){
      const float* wp = w + ((size_t)oc*IC+icb)*5;
      for (int ic=0;ic<icn;ic++){
        float xw[36];
        #pragma unroll
        for (int q=0;q<9;q++) ((float4*)xw)[q]=((const float4*)(xs+ic*36))[q];
        float wk0=wp[ic*5  ],wk1=wp[ic*5+1],wk2=wp[ic*5+2],
              wk3=wp[ic*5+3],wk4=wp[ic*5+4];
        #pragma unroll
        for (int tt=0;tt<32;tt++)
          acc[tt] += wk0*xw[tt]+wk1*xw[tt+1]+wk2*xw[tt+2]+wk3*xw[tt+3]+wk4*xw[tt+4];
      }
    }
  }
  if (oc<OC){
    float bv=bias[oc];
    for (int tt=0;tt<32;tt++){
      int tg=t0+tt;
      if (tg<TD){
        float v=acc[tt]+bv;
        if (do_tanh) v=tanhfast(v);
        out[((size_t)bl*OC+oc)*TD+tg]=__float2bfloat16(v);
      }
    }
  }
}

// ---------------- postnet last layer + in-place residual on d_out ----------
__global__ __launch_bounds__(256) void k_conv_last(
    const bf16* __restrict__ in, const float* __restrict__ w,
    const float* __restrict__ bias, float* __restrict__ outp, int b0)
{
  __shared__ __align__(16) float xs[256*36];
  int bl=blockIdx.x, bg=b0+bl, t0=blockIdx.z*32, tid=threadIdx.x;
  int oc = tid;
  float acc[32];
  #pragma unroll
  for (int q=0;q<32;q++) acc[q]=0.f;
  for (int ch=0;ch<2;ch++){
    int icb=ch*256;
    __syncthreads();
    for (int i=tid;i<256*36;i+=256){
      int icl=i/36, tt=i-icl*36;
      int tg=t0+tt-2;
      float v=0.f;
      if (tg>=0 && tg<TD){
        int ic=icb+icl;
        v = b2f(in[((size_t)bl*PH+ic)*TD+tg]);
      }
      xs[i]=v;
    }
    __syncthreads();
    if (oc<TGT){
      const float* wp = w + ((size_t)oc*PH+icb)*5;
      for (int ic=0;ic<256;ic++){
        float xw[36];
        #pragma unroll
        for (int q=0;q<9;q++) ((float4*)xw)[q]=((const float4*)(xs+ic*36))[q];
        float wk0=wp[ic*5  ],wk1=wp[ic*5+1],wk2=wp[ic*5+2],
              wk3=wp[ic*5+3],wk4=wp[ic*5+4];
        #pragma unroll
        for (int tt=0;tt<32;tt++)
          acc[tt] += wk0*xw[tt]+wk1*xw[tt+1]+wk2*xw[tt+2]+wk3*xw[tt+3]+wk4*xw[tt+4];
      }
    }
  }
  if (oc<TGT){
    float bv=bias[oc];
    for (int tt=0;tt<32;tt++){
      int tg=t0+tt;
      if (tg<TD){
        size_t idx=((size_t)bg*TD+tg)*TGT+oc;
        outp[idx]=acc[tt]+bv+outp[idx];
      }
    }
  }
}

extern "C" void kernel_launch(void* const* d_in, const int* in_sizes, int n_in,
                              void* d_out, int out_size, void* d_ws, size_t ws_size,
                              hipStream_t stream)
{
  const float* enc =(const float*)d_in[0];
  const float* dec =(const float*)d_in[1];
  const float* pw1 =(const float*)d_in[2];  const float* pb1=(const float*)d_in[3];
  const float* pw2 =(const float*)d_in[4];  const float* pb2=(const float*)d_in[5];
  const float* awih=(const float*)d_in[6];  const float* awhh=(const float*)d_in[7];
  const float* abih=(const float*)d_in[8];  const float* abhh=(const float*)d_in[9];
  const float* dwih=(const float*)d_in[10]; const float* dwhh=(const float*)d_in[11];
  const float* dbih=(const float*)d_in[12]; const float* dbhh=(const float*)d_in[13];
  const float* memw=(const float*)d_in[14]; const float* memb=(const float*)d_in[15];
  const float* qw  =(const float*)d_in[16];
  const float* lcw =(const float*)d_in[17];
  const float* lfw =(const float*)d_in[18];
  const float* vw  =(const float*)d_in[19];
  const float* pjw =(const float*)d_in[20];
  const float* cwt0=(const float*)d_in[21]; const float* cbt0=(const float*)d_in[22];
  const float* cwt1=(const float*)d_in[23]; const float* cbt1=(const float*)d_in[24];
  const float* cwt2=(const float*)d_in[25]; const float* cbt2=(const float*)d_in[26];
  const float* cwt3=(const float*)d_in[27]; const float* cbt3=(const float*)d_in[28];
  const float* cwt4=(const float*)d_in[29]; const float* cbt4=(const float*)d_in[30];
  float* MEL = (float*)d_out;
  (void)in_sizes; (void)n_in; (void)out_size; (void)ws_size;

  // ---- workspace layout: ----
  char* base=(char*)d_ws;
  const size_t XS_B = (size_t)TD*NB*PREN*2;   //  9,830,400 B
  const size_t PM_B = (size_t)NB*TE*ATTD*2;   //  4,915,200 B
  const size_t HB   = (size_t)NB*HID*4;       //     65,536 B
  const size_t WB   = (size_t)NB*TE*4;        //     76,800 B
  bf16* XSb = (bf16*)base;
  bf16* PMb = (bf16*)(base + XS_B);
  char* sbase = base + XS_B + PM_B;
  float* AH0b=(float*)(sbase+0*HB);
  float* AH1b=(float*)(sbase+1*HB);
  float* ACb =(float*)(sbase+2*HB);
  float* DH0b=(float*)(sbase+3*HB);
  float* DH1b=(float*)(sbase+4*HB);
  float* DCb =(float*)(sbase+5*HB);
  float* CTX =(float*)(sbase+6*HB);
  float* Wb  =(float*)(sbase+7*HB);
  float* WC  =(float*)(sbase+7*HB+WB);
  float* Eb  =(float*)(sbase+7*HB+2*WB);
  const int G = 8;
  const size_t PBc_B = (size_t)G*PH*TD*2;
  bf16* PB0 = (bf16*)base;
  bf16* PB1 = (bf16*)(base + PBc_B);

  hipMemsetAsync(sbase, 0, 7*HB+3*WB, stream);

  k_prenet<<<TD,256,0,stream>>>(dec,pw1,pb1,pw2,pb2,XSb);
  k_procmem<<<TE,256,0,stream>>>(enc,memw,memb,PMb);

  // prologue: lstmA(0) only
  k_lstmAD<<<256,256,0,stream>>>(XSb,CTX,AH0b,AH1b,ACb,DH0b,DH1b,DCb,
                                 awih,awhh,abih,abhh,dwih,dwhh,dbih,dbhh,-1);
  for (int t=0;t<TD;t++){
    const float* AHn = (t&1)? AH0b : AH1b;   // AH'(t)
    const float* DHp = (t&1)? DH1b : DH0b;   // DH(t-1)
    k_att1m<<<256,256,0,stream>>>(AHn,Wb,WC,PMb,Eb,qw,lcw,lfw,vw,DHp,CTX,pjw,MEL,t);
    k_att23<<<256,256,0,stream>>>(Eb,Wb,WC,enc,CTX);
    k_lstmAD<<<256,256,0,stream>>>(XSb,CTX,AH0b,AH1b,ACb,DH0b,DH1b,DCb,
                                   awih,awhh,abih,abhh,dwih,dwhh,dbih,dbhh,t);
  }
  // after t=599 (odd), DH(599) is in DH0
  k_melfinal<<<10,256,0,stream>>>(DH0b,CTX,pjw,MEL);

  // postnet in 4 batch-chunks of G=8 (buffers fit the dead XS region)
  for (int c=0;c<NB/G;c++){
    int b0=c*G;
    k_conv<<<dim3(G,2,19),256,0,stream>>>(MEL,PB0,cwt0,cbt0,TGT,PH,1,1,b0);
    k_conv<<<dim3(G,2,19),256,0,stream>>>(PB0,PB1,cwt1,cbt1,PH,PH,0,1,b0);
    k_conv<<<dim3(G,2,19),256,0,stream>>>(PB1,PB0,cwt2,cbt2,PH,PH,0,1,b0);
    k_conv<<<dim3(G,2,19),256,0,stream>>>(PB0,PB1,cwt3,cbt3,PH,PH,0,1,b0);
    k_conv_last<<<dim3(G,1,19),256,0,stream>>>(PB1,cwt4,cbt4,MEL,b0);
  }
}

// Round 3
// 63228.021 us; speedup vs baseline: 2.2508x; 1.4043x over previous
//
#include <hip/hip_runtime.h>
#include <hip/hip_bf16.h>

typedef __hip_bfloat16 bf16;

#define NB   32
#define TE   600
#define TD   600
#define TGT  80
#define PREN 256
#define HID  512
#define ATTD 128
#define LF   32
#define LK   31
#define PH   512

__device__ __forceinline__ float b2f(bf16 x){ return __bfloat162float(x); }

// 8 contiguous bf16 -> fp32 (internal ws tensors only)
__device__ __forceinline__ void ld8bf(const bf16* p, float* o){
  const uint4 u = *(const uint4*)p;
  o[0]=__uint_as_float(u.x<<16); o[1]=__uint_as_float(u.x&0xFFFF0000u);
  o[2]=__uint_as_float(u.y<<16); o[3]=__uint_as_float(u.y&0xFFFF0000u);
  o[4]=__uint_as_float(u.z<<16); o[5]=__uint_as_float(u.z&0xFFFF0000u);
  o[6]=__uint_as_float(u.w<<16); o[7]=__uint_as_float(u.w&0xFFFF0000u);
}

// 8 contiguous fp32
__device__ __forceinline__ void ld8f(const float* p, float* o){
  float4 a=*(const float4*)p, b=*(const float4*)(p+4);
  o[0]=a.x;o[1]=a.y;o[2]=a.z;o[3]=a.w;
  o[4]=b.x;o[5]=b.y;o[6]=b.z;o[7]=b.w;
}

__device__ __forceinline__ float dot8(const float* w, const float* z){
  return w[0]*z[0]+w[1]*z[1]+w[2]*z[2]+w[3]*z[3]
       + w[4]*z[4]+w[5]*z[5]+w[6]*z[6]+w[7]*z[7];
}

__device__ __forceinline__ float sigm(float x){ return 1.f/(1.f+__expf(-x)); }
__device__ __forceinline__ float tanhfast(float x){
  float e = __expf(2.f*x);
  return 1.f - 2.f/(e+1.f);
}

// ---------------- prenet: XS[t][b][256] (bf16) -----------------
__global__ __launch_bounds__(256) void k_prenet(const float* __restrict__ dec,
    const float* __restrict__ w1, const float* __restrict__ b1,
    const float* __restrict__ w2, const float* __restrict__ b2,
    bf16* __restrict__ XS)
{
  int t = blockIdx.x, tid = threadIdx.x;
  __shared__ __align__(16) float fr[NB*TGT];
  __shared__ __align__(16) float h1[NB*PREN];
  for (int i=tid;i<NB*TGT;i+=256){
    int b=i/TGT,c=i%TGT;
    fr[b*TGT+c] = (t==0)?0.f:dec[((size_t)b*TD+(t-1))*TGT+c];
  }
  __syncthreads();
  {
    int oc=tid; float bb=b1[oc];
    const float* wr = w1 + (size_t)oc*TGT;
    for (int b=0;b<NB;b++){
      float acc=bb;
      for (int k=0;k<TGT;k+=8){
        float wv[8]; ld8f(wr+k,wv);
        acc += dot8(wv, fr + b*TGT + k);
      }
      h1[b*PREN+oc]=fmaxf(acc,0.f);
    }
  }
  __syncthreads();
  {
    int oc=tid; float bb=b2[oc];
    const float* wr = w2 + (size_t)oc*PREN;
    for (int b=0;b<NB;b++){
      float acc=bb;
      for (int k=0;k<PREN;k+=8){
        float wv[8]; ld8f(wr+k,wv);
        acc += dot8(wv, h1 + b*PREN + k);
      }
      XS[((size_t)t*NB+b)*PREN+oc]=__float2bfloat16(fmaxf(acc,0.f));
    }
  }
}

// ---------------- proc_mem: PM[b][t][128] (bf16) -----------------
__global__ __launch_bounds__(256) void k_procmem(const float* __restrict__ enc,
    const float* __restrict__ mw, const float* __restrict__ mb, bf16* __restrict__ PM)
{
  int t=blockIdx.x, tid=threadIdx.x;
  __shared__ __align__(16) float xe[16*HID];
  int a = tid & 127, bh = tid >> 7;
  float bb = mb[a];
  const float* wr = mw + (size_t)a*HID;
  for (int half=0; half<2; half++){
    __syncthreads();
    for (int i=tid;i<16*HID;i+=256){
      int bl=i>>9, h=i&511;
      xe[i] = enc[((size_t)(half*16+bl)*TE + t)*HID + h];
    }
    __syncthreads();
    for (int bl=bh*8; bl<bh*8+8; bl++){
      float acc=bb;
      for (int k=0;k<HID;k+=8){
        float wv[8]; ld8f(wr+k,wv);
        acc += dot8(wv, xe + bl*HID + k);
      }
      PM[((size_t)(half*16+bl)*TE + t)*ATTD + a] = __float2bfloat16(acc);
    }
  }
}

// ---------------- phase 1: energies + q-proj + mel(t-1) -----------------
// grid 512: b = blk&31, chunk = blk>>5 (16 chunks of 38 t), block 256
__global__ __launch_bounds__(256) void k_att1m(
    const float* __restrict__ AHn, const float* __restrict__ W,
    const float* __restrict__ WCUM, const bf16* __restrict__ PM,
    float* __restrict__ E,
    const float* __restrict__ qw, const float* __restrict__ convw,
    const float* __restrict__ fcw, const float* __restrict__ vw,
    const float* __restrict__ DHp, const float* __restrict__ CTX,
    const float* __restrict__ projw, float* __restrict__ MEL, int t)
{
  int blk = blockIdx.x, tid = threadIdx.x;
  int b = blk & 31, chunk = blk >> 5;
  __shared__ __align__(16) float wpad[632], wcpad[632], qs[128], vv[128];
  __shared__ __align__(16) float fcs[128*33];
  __shared__ __align__(16) float cw0[32*31], cw1[32*31];
  __shared__ __align__(16) float convb[4][32];
  for (int i=tid;i<630;i+=256){
    wpad[i]  = (i>=15 && i<615) ? W[(size_t)b*TE + i-15] : 0.f;
    wcpad[i] = (i>=15 && i<615) ? WCUM[(size_t)b*TE + i-15] : 0.f;
  }
  for (int i=tid;i<32*31;i+=256){
    int c=i/31, k=i-c*31;
    cw0[i] = convw[c*62 + k];
    cw1[i] = convw[c*62 + 31 + k];
  }
  for (int i=tid;i<128*33;i+=256){
    int a=i/33, c=i-a*33;
    fcs[i] = (c<32)? fcw[a*32+c] : 0.f;
  }
  if (tid < 128){
    vv[tid] = vw[tid];
    const float* qr = qw + (size_t)tid*HID;
    const float* ah = AHn + b*HID;
    float acc = 0.f;
    for (int k=0;k<HID;k+=8){
      float wv[8]; ld8f(qr+k,wv);
      acc += dot8(wv, ah+k);
    }
    qs[tid] = acc;
  }
  // mel for step t-1: reads DH(t-1), CTX(t-1) -- both stable this phase.
  // 2560 outputs over 512 blocks -> 5 per block, threads 0..39
  if (t>0 && tid<40){
    int md = blk*5 + (tid>>3);
    int jb = tid&7;
    int o = md%TGT, bb = md/TGT;
    const float* pw = projw + (size_t)o*1024;
    const float* dh = DHp + bb*HID;
    const float* c2 = CTX + bb*HID;
    float a=0.f;
    for (int i=0;i<16;i++){
      int k = jb*128 + i*8;
      const float* zp = (k<512)? dh+k : c2+(k-512);
      float z[8]; ld8f(zp,z);
      float wv[8]; ld8f(pw+k,wv);
      a += dot8(wv,z);
    }
    a += __shfl_xor(a,1); a += __shfl_xor(a,2); a += __shfl_xor(a,4);
    if (jb==0) MEL[((size_t)bb*TD + (t-1))*TGT + o] = a;
  }
  __syncthreads();
  int wid = tid>>6, lane = tid&63;
  int tbase = chunk*38;
  int tend  = min(tbase+38, TE);
  for (int it=0; it<10; it++){
    int tt = tbase + it*4 + wid;
    bool act = (tt < tend);
    if (act && lane < 32){
      int c = lane; float s = 0.f;
      for (int k=0;k<LK;k++)
        s += cw0[c*31+k]*wpad[tt+k] + cw1[c*31+k]*wcpad[tt+k];
      convb[wid][c] = s;
    }
    __syncthreads();
    if (act){
      float part = 0.f;
      #pragma unroll
      for (int half=0; half<2; half++){
        int a = lane + half*64;
        float loc = 0.f;
        #pragma unroll
        for (int c=0;c<32;c++) loc += fcs[a*33+c]*convb[wid][c];
        float x = qs[a] + b2f(PM[((size_t)b*TE + tt)*ATTD + a]) + loc;
        part += vv[a]*tanhfast(x);
      }
      for (int off=1; off<64; off<<=1) part += __shfl_xor(part, off);
      if (lane==0) E[(size_t)b*TE + tt] = part;
    }
    __syncthreads();
  }
}

// ---------------- phase 2: softmax (redundant per block) + ctx slice ------
// grid 512: b = blk>>4, q16 = blk&15 (32 h each), block 256
__global__ __launch_bounds__(256) void k_att23(const float* __restrict__ E,
    float* __restrict__ W, float* __restrict__ WCUM,
    const float* __restrict__ enc, float* __restrict__ CTX)
{
  int blk=blockIdx.x, tid=threadIdx.x;
  int b = blk>>4, q16 = blk&15;
  __shared__ __align__(16) float wl[600];
  __shared__ float part[256];
  __shared__ float red[4];
  float e0[3]; float mx=-1e30f;
  #pragma unroll
  for (int r=0;r<3;r++){
    int i=tid+r*256;
    float v=(i<TE)? E[(size_t)b*TE+i] : -1e30f;
    e0[r]=v; mx=fmaxf(mx,v);
  }
  for (int off=1;off<64;off<<=1) mx=fmaxf(mx,__shfl_xor(mx,off));
  if ((tid&63)==0) red[tid>>6]=mx;
  __syncthreads();
  float m=fmaxf(fmaxf(red[0],red[1]),fmaxf(red[2],red[3]));
  float ex[3]; float s=0.f;
  #pragma unroll
  for (int r=0;r<3;r++){
    int i=tid+r*256;
    ex[r]=(i<TE)? __expf(e0[r]-m) : 0.f;
    s+=ex[r];
  }
  for (int off=1;off<64;off<<=1) s+=__shfl_xor(s,off);
  __syncthreads();
  if ((tid&63)==0) red[tid>>6]=s;
  __syncthreads();
  float inv=1.f/(red[0]+red[1]+red[2]+red[3]);
  #pragma unroll
  for (int r=0;r<3;r++){
    int i=tid+r*256;
    if (i<TE){
      float w2=ex[r]*inv;
      wl[i]=w2;
      if (q16==0){
        W[(size_t)b*TE+i]=w2;
        WCUM[(size_t)b*TE+i]+=w2;
      }
    }
  }
  __syncthreads();
  {
    int hl=tid&31, tj=tid>>5;            // 8 t-lanes x 75 t
    int h=q16*32+hl;
    const float* ep = enc + ((size_t)b*TE)*HID + h;
    int tb_=tj*75;
    float a0=0.f,a1=0.f,a2=0.f;
    for (int u=0;u<25;u++){
      int tt=tb_+u*3;
      a0 += wl[tt  ]*ep[(size_t)(tt  )*HID];
      a1 += wl[tt+1]*ep[(size_t)(tt+1)*HID];
      a2 += wl[tt+2]*ep[(size_t)(tt+2)*HID];
    }
    part[tid]=a0+a1+a2;
  }
  __syncthreads();
  if (tid<32){
    float v=0.f;
    #pragma unroll
    for (int k=0;k<8;k++) v += part[tid + 32*k];
    CTX[b*HID + q16*32 + tid]=v;
  }
}

// ---------------- phase 3: lstmD(t) || lstmA(t+1), 1 cell per block -------
// blocks 0..511: lstmA step t+1; blocks 512..1023: lstmD step t
__global__ __launch_bounds__(256) void k_lstmAD(
    const bf16* __restrict__ XS, const float* __restrict__ CTX,
    float* __restrict__ AH0, float* __restrict__ AH1, float* __restrict__ AC,
    float* __restrict__ DH0, float* __restrict__ DH1, float* __restrict__ DC,
    const float* __restrict__ awih, const float* __restrict__ awhh,
    const float* __restrict__ abih, const float* __restrict__ abhh,
    const float* __restrict__ dwih, const float* __restrict__ dwhh,
    const float* __restrict__ dbih, const float* __restrict__ dbhh,
    int t)
{
  int blk=blockIdx.x, tid=threadIdx.x;
  int b=tid>>3, j=tid&7;
  if (blk<512){
    int s = t+1;                       // attention-LSTM step
    if (s>=TD) return;
    int cell = blk;
    const bf16* xs = XS + ((size_t)s*NB+b)*PREN;
    const float* cx = CTX + b*HID;
    const float* hr = ((s&1)?AH1:AH0) + b*HID;
    float* hw = (s&1)?AH0:AH1;
    float acc[4];
    #pragma unroll
    for (int q=0;q<4;q++) acc[q]=0.f;
    for (int i=0;i<20;i++){
      int k8=i*64+j*8;
      float z[8];
      if (k8<256) ld8bf(xs+k8,z);
      else ld8f((k8<768)? cx+(k8-256) : hr+(k8-768), z);
      #pragma unroll
      for (int g=0;g<4;g++){
        int row = g*HID + cell;
        const float* wp = (k8<768) ? (awih + (size_t)row*768 + k8)
                                   : (awhh + (size_t)row*HID + (k8-768));
        float wv[8]; ld8f(wp,wv);
        acc[g] += dot8(wv,z);
      }
    }
    #pragma unroll
    for (int q=0;q<4;q++){
      acc[q] += __shfl_xor(acc[q],1);
      acc[q] += __shfl_xor(acc[q],2);
      acc[q] += __shfl_xor(acc[q],4);
    }
    if (j==0){
      float g0=acc[0]+abih[0*HID+cell]+abhh[0*HID+cell];
      float g1=acc[1]+abih[1*HID+cell]+abhh[1*HID+cell];
      float g2=acc[2]+abih[2*HID+cell]+abhh[2*HID+cell];
      float g3=acc[3]+abih[3*HID+cell]+abhh[3*HID+cell];
      float c2 = sigm(g1)*AC[b*HID+cell] + sigm(g0)*tanhfast(g2);
      AC[b*HID+cell]=c2;
      hw[b*HID+cell]=sigm(g3)*tanhfast(c2);
    }
  } else {
    if (t<0) return;
    int cell = blk-512;
    const float* ah  = ((t&1)?AH0:AH1) + b*HID;   // AH'(t)
    const float* cx  = CTX + b*HID;
    const float* dhr = ((t&1)?DH1:DH0) + b*HID;
    float* dhw = (t&1)?DH0:DH1;
    float acc[4];
    #pragma unroll
    for (int q=0;q<4;q++) acc[q]=0.f;
    for (int i=0;i<24;i++){
      int k8=i*64+j*8;
      const float* zp = (k8<512)? ah+k8 : (k8<1024)? cx+(k8-512) : dhr+(k8-1024);
      float z[8]; ld8f(zp,z);
      #pragma unroll
      for (int g=0;g<4;g++){
        int row = g*HID + cell;
        const float* wp = (k8<1024) ? (dwih + (size_t)row*1024 + k8)
                                    : (dwhh + (size_t)row*HID + (k8-1024));
        float wv[8]; ld8f(wp,wv);
        acc[g] += dot8(wv,z);
      }
    }
    #pragma unroll
    for (int q=0;q<4;q++){
      acc[q] += __shfl_xor(acc[q],1);
      acc[q] += __shfl_xor(acc[q],2);
      acc[q] += __shfl_xor(acc[q],4);
    }
    if (j==0){
      float g0=acc[0]+dbih[0*HID+cell]+dbhh[0*HID+cell];
      float g1=acc[1]+dbih[1*HID+cell]+dbhh[1*HID+cell];
      float g2=acc[2]+dbih[2*HID+cell]+dbhh[2*HID+cell];
      float g3=acc[3]+dbih[3*HID+cell]+dbhh[3*HID+cell];
      float c2 = sigm(g1)*DC[b*HID+cell] + sigm(g0)*tanhfast(g2);
      DC[b*HID+cell]=c2;
      dhw[b*HID+cell]=sigm(g3)*tanhfast(c2);
    }
  }
}

// ---------------- final-step mel -----------------
__global__ __launch_bounds__(256) void k_melfinal(const float* __restrict__ DH,
    const float* __restrict__ CTX, const float* __restrict__ projw, float* __restrict__ MEL)
{
  int gid=blockIdx.x*256+threadIdx.x;
  if (gid>=NB*TGT) return;
  int o=gid%TGT, b=gid/TGT;
  const float* pw=projw+(size_t)o*1024;
  float a=0.f;
  for (int k=0;k<HID;k+=8){
    float wv[8]; ld8f(pw+k,wv);
    a += dot8(wv, DH + b*HID + k);
  }
  for (int k=0;k<HID;k+=8){
    float wv[8]; ld8f(pw+512+k,wv);
    a += dot8(wv, CTX + b*HID + k);
  }
  MEL[((size_t)b*TD+599)*TGT+o]=a;
}

// ---------------- postnet conv (generic, bf16 internal activations) --------
__global__ __launch_bounds__(256) void k_conv(
    const void* __restrict__ inv_, bf16* __restrict__ out,
    const float* __restrict__ w, const float* __restrict__ bias,
    int IC, int OC, int mel_in, int do_tanh, int b0)
{
  __shared__ __align__(16) float xs[256*36];
  int bl=blockIdx.x, bg=b0+bl, oct=blockIdx.y, t0=blockIdx.z*32, tid=threadIdx.x;
  int oc = oct*256 + tid;
  float acc[32];
  #pragma unroll
  for (int q=0;q<32;q++) acc[q]=0.f;
  int nch=(IC+255)/256;
  const float* inf_ = (const float*)inv_;
  const bf16*  inb_ = (const bf16*)inv_;
  for (int ch=0;ch<nch;ch++){
    int icb=ch*256, icn=min(256,IC-icb);
    __syncthreads();
    for (int i=tid;i<icn*36;i+=256){
      int icl=i/36, tt=i-icl*36;
      int tg=t0+tt-2;
      float v=0.f;
      if (tg>=0 && tg<TD){
        int ic=icb+icl;
        v = mel_in ? inf_[((size_t)bg*TD+tg)*TGT+ic]
                   : b2f(inb_[((size_t)bl*IC+ic)*TD+tg]);
      }
      xs[i]=v;
    }
    __syncthreads();
    if (oc<OC){
      const float* wp = w + ((size_t)oc*IC+icb)*5;
      for (int ic=0;ic<icn;ic++){
        float xw[36];
        #pragma unroll
        for (int q=0;q<9;q++) ((float4*)xw)[q]=((const float4*)(xs+ic*36))[q];
        float wk0=wp[ic*5  ],wk1=wp[ic*5+1],wk2=wp[ic*5+2],
              wk3=wp[ic*5+3],wk4=wp[ic*5+4];
        #pragma unroll
        for (int tt=0;tt<32;tt++)
          acc[tt] += wk0*xw[tt]+wk1*xw[tt+1]+wk2*xw[tt+2]+wk3*xw[tt+3]+wk4*xw[tt+4];
      }
    }
  }
  if (oc<OC){
    float bv=bias[oc];
    for (int tt=0;tt<32;tt++){
      int tg=t0+tt;
      if (tg<TD){
        float v=acc[tt]+bv;
        if (do_tanh) v=tanhfast(v);
        out[((size_t)bl*OC+oc)*TD+tg]=__float2bfloat16(v);
      }
    }
  }
}

// ---------------- postnet last layer + in-place residual on d_out ----------
__global__ __launch_bounds__(256) void k_conv_last(
    const bf16* __restrict__ in, const float* __restrict__ w,
    const float* __restrict__ bias, float* __restrict__ outp, int b0)
{
  __shared__ __align__(16) float xs[256*36];
  int bl=blockIdx.x, bg=b0+bl, t0=blockIdx.z*32, tid=threadIdx.x;
  int oc = tid;
  float acc[32];
  #pragma unroll
  for (int q=0;q<32;q++) acc[q]=0.f;
  for (int ch=0;ch<2;ch++){
    int icb=ch*256;
    __syncthreads();
    for (int i=tid;i<256*36;i+=256){
      int icl=i/36, tt=i-icl*36;
      int tg=t0+tt-2;
      float v=0.f;
      if (tg>=0 && tg<TD){
        int ic=icb+icl;
        v = b2f(in[((size_t)bl*PH+ic)*TD+tg]);
      }
      xs[i]=v;
    }
    __syncthreads();
    if (oc<TGT){
      const float* wp = w + ((size_t)oc*PH+icb)*5;
      for (int ic=0;ic<256;ic++){
        float xw[36];
        #pragma unroll
        for (int q=0;q<9;q++) ((float4*)xw)[q]=((const float4*)(xs+ic*36))[q];
        float wk0=wp[ic*5  ],wk1=wp[ic*5+1],wk2=wp[ic*5+2],
              wk3=wp[ic*5+3],wk4=wp[ic*5+4];
        #pragma unroll
        for (int tt=0;tt<32;tt++)
          acc[tt] += wk0*xw[tt]+wk1*xw[tt+1]+wk2*xw[tt+2]+wk3*xw[tt+3]+wk4*xw[tt+4];
      }
    }
  }
  if (oc<TGT){
    float bv=bias[oc];
    for (int tt=0;tt<32;tt++){
      int tg=t0+tt;
      if (tg<TD){
        size_t idx=((size_t)bg*TD+tg)*TGT+oc;
        outp[idx]=acc[tt]+bv+outp[idx];
      }
    }
  }
}

extern "C" void kernel_launch(void* const* d_in, const int* in_sizes, int n_in,
                              void* d_out, int out_size, void* d_ws, size_t ws_size,
                              hipStream_t stream)
{
  const float* enc =(const float*)d_in[0];
  const float* dec =(const float*)d_in[1];
  const float* pw1 =(const float*)d_in[2];  const float* pb1=(const float*)d_in[3];
  const float* pw2 =(const float*)d_in[4];  const float* pb2=(const float*)d_in[5];
  const float* awih=(const float*)d_in[6];  const float* awhh=(const float*)d_in[7];
  const float* abih=(const float*)d_in[8];  const float* abhh=(const float*)d_in[9];
  const float* dwih=(const float*)d_in[10]; const float* dwhh=(const float*)d_in[11];
  const float* dbih=(const float*)d_in[12]; const float* dbhh=(const float*)d_in[13];
  const float* memw=(const float*)d_in[14]; const float* memb=(const float*)d_in[15];
  const float* qw  =(const float*)d_in[16];
  const float* lcw =(const float*)d_in[17];
  const float* lfw =(const float*)d_in[18];
  const float* vw  =(const float*)d_in[19];
  const float* pjw =(const float*)d_in[20];
  const float* cwt0=(const float*)d_in[21]; const float* cbt0=(const float*)d_in[22];
  const float* cwt1=(const float*)d_in[23]; const float* cbt1=(const float*)d_in[24];
  const float* cwt2=(const float*)d_in[25]; const float* cbt2=(const float*)d_in[26];
  const float* cwt3=(const float*)d_in[27]; const float* cbt3=(const float*)d_in[28];
  const float* cwt4=(const float*)d_in[29]; const float* cbt4=(const float*)d_in[30];
  float* MEL = (float*)d_out;
  (void)in_sizes; (void)n_in; (void)out_size; (void)ws_size;

  // ---- workspace layout: ----
  char* base=(char*)d_ws;
  const size_t XS_B = (size_t)TD*NB*PREN*2;   //  9,830,400 B
  const size_t PM_B = (size_t)NB*TE*ATTD*2;   //  4,915,200 B
  const size_t HB   = (size_t)NB*HID*4;       //     65,536 B
  const size_t WB   = (size_t)NB*TE*4;        //     76,800 B
  bf16* XSb = (bf16*)base;
  bf16* PMb = (bf16*)(base + XS_B);
  char* sbase = base + XS_B + PM_B;
  float* AH0b=(float*)(sbase+0*HB);
  float* AH1b=(float*)(sbase+1*HB);
  float* ACb =(float*)(sbase+2*HB);
  float* DH0b=(float*)(sbase+3*HB);
  float* DH1b=(float*)(sbase+4*HB);
  float* DCb =(float*)(sbase+5*HB);
  float* CTX =(float*)(sbase+6*HB);
  float* Wb  =(float*)(sbase+7*HB);
  float* WC  =(float*)(sbase+7*HB+WB);
  float* Eb  =(float*)(sbase+7*HB+2*WB);
  const int G = 8;
  const size_t PBc_B = (size_t)G*PH*TD*2;
  bf16* PB0 = (bf16*)base;
  bf16* PB1 = (bf16*)(base + PBc_B);

  hipMemsetAsync(sbase, 0, 7*HB+3*WB, stream);

  k_prenet<<<TD,256,0,stream>>>(dec,pw1,pb1,pw2,pb2,XSb);
  k_procmem<<<TE,256,0,stream>>>(enc,memw,memb,PMb);

  // prologue: lstmA(0) only
  k_lstmAD<<<1024,256,0,stream>>>(XSb,CTX,AH0b,AH1b,ACb,DH0b,DH1b,DCb,
                                  awih,awhh,abih,abhh,dwih,dwhh,dbih,dbhh,-1);
  for (int t=0;t<TD;t++){
    const float* AHn = (t&1)? AH0b : AH1b;   // AH'(t)
    const float* DHp = (t&1)? DH1b : DH0b;   // DH(t-1)
    k_att1m<<<512,256,0,stream>>>(AHn,Wb,WC,PMb,Eb,qw,lcw,lfw,vw,DHp,CTX,pjw,MEL,t);
    k_att23<<<512,256,0,stream>>>(Eb,Wb,WC,enc,CTX);
    k_lstmAD<<<1024,256,0,stream>>>(XSb,CTX,AH0b,AH1b,ACb,DH0b,DH1b,DCb,
                                    awih,awhh,abih,abhh,dwih,dwhh,dbih,dbhh,t);
  }
  // after t=599 (odd), DH(599) is in DH0
  k_melfinal<<<10,256,0,stream>>>(DH0b,CTX,pjw,MEL);

  // postnet in 4 batch-chunks of G=8 (buffers fit the dead XS region)
  for (int c=0;c<NB/G;c++){
    int b0=c*G;
    k_conv<<<dim3(G,2,19),256,0,stream>>>(MEL,PB0,cwt0,cbt0,TGT,PH,1,1,b0);
    k_conv<<<dim3(G,2,19),256,0,stream>>>(PB0,PB1,cwt1,cbt1,PH,PH,0,1,b0);
    k_conv<<<dim3(G,2,19),256,0,stream>>>(PB1,PB0,cwt2,cbt2,PH,PH,0,1,b0);
    k_conv<<<dim3(G,2,19),256,0,stream>>>(PB0,PB1,cwt3,cbt3,PH,PH,0,1,b0);
    k_conv_last<<<dim3(G,1,19),256,0,stream>>>(PB1,cwt4,cbt4,MEL,b0);
  }
}